// Round 4
// baseline (748.694 us; speedup 1.0000x reference)
//
#include <hip/hip_runtime.h>
#include <hip/hip_fp16.h>

// Weight-stationary LSTM classifier, XCD-chunked + 3-deep A pipeline.
// B=4096(+64 pad), T=22, E=H=300. Grid 248 = 8 XCDs x 31 slots; logical
// L = (b&7)*31 + b/8 so each XCD hosts contiguous mb-major wg ids (A-panel
// L2 locality). L in [0,247): mb = L/19 (320 rows), nb = L%19 (16 jh x 4
// gates). W block (64 cols x 608 k fp16 = 79KB) LDS-stationary for all 22
// steps. Per step: gates = A @ W with A = [x|h] fp16 from global double
// buffer, A-chunks (32-k) register-pipelined 3 deep; i/f/g/o same-lane
// combine; h fp16 back to the other buffer; one device barrier per step.
// d_ws: [0..256) barrier counter, then 2 x 4160x608 fp16 buffers (10.1 MB).

#define TT 22
#define STEPS 22
#define NB 19
#define MBC 13
#define NACT (NB * MBC)          // 247 active
#define NWG 248                  // + 1 dummy (barrier-only)
#define XSTR 608                 // halves per A row (300 x | 300 h | 8 pad)
#define WLS 616                  // LDS W col stride (halves)
#define BUFROWS 4160
#define BUFELT ((size_t)BUFROWS * XSTR)

typedef _Float16 f16;
typedef _Float16 f16x8 __attribute__((ext_vector_type(8)));
typedef float    f32x4 __attribute__((ext_vector_type(4)));

__device__ __forceinline__ float sigm(float x) { return 1.0f / (1.0f + __expf(-x)); }
__device__ __forceinline__ float tanh_f(float x) {
    float ax = fabsf(x);
    float e = __expf(-2.0f * ax);
    return copysignf((1.0f - e) / (1.0f + e), x);
}

__global__ __launch_bounds__(256, 1)
void lstm_ws(const int* __restrict__ cap, const int* __restrict__ cap_len,
             const float* __restrict__ embed,
             const float* __restrict__ Wih, const float* __restrict__ Whh,
             const float* __restrict__ bih, const float* __restrict__ bhh,
             const float* __restrict__ v_wn, const float* __restrict__ g_wn,
             const float* __restrict__ b_cls,
             f16* __restrict__ buf0, f16* __restrict__ buf1,
             unsigned* __restrict__ cnt, float* __restrict__ out)
{
    __shared__ f16 Wl[64 * WLS];     // 78.8 KB stationary weights
    __shared__ int capS[17][TT];
    __shared__ float scaleS[2];

    const int tid = threadIdx.x;
    const int b   = blockIdx.x;
    const int L   = (b & 7) * 31 + (b >> 3);   // XCD-chunked logical id

    unsigned bk = 0;
    auto gbar = [&]() {
        ++bk;
        __syncthreads();
        if (tid == 0) {
            __hip_atomic_fetch_add(cnt, 1u, __ATOMIC_RELEASE, __HIP_MEMORY_SCOPE_AGENT);
            unsigned tgt = bk * NWG;
            while (__hip_atomic_load(cnt, __ATOMIC_RELAXED, __HIP_MEMORY_SCOPE_AGENT) < tgt)
                __builtin_amdgcn_s_sleep(2);
            (void)__hip_atomic_load(cnt, __ATOMIC_ACQUIRE, __HIP_MEMORY_SCOPE_AGENT);
        }
        __syncthreads();
    };

    if (L >= NACT) {                  // dummy wg: barriers only (23 total)
        for (int i = 0; i < STEPS + 1; ++i) gbar();
        return;
    }

    const int mb = L / NB;
    const int nb = L - mb * NB;
    const int mrow0 = mb * 320;
    const int wv = tid >> 6, ln = tid & 63, c = ln & 15, kg = ln >> 4;

    // ---- W block -> LDS (fp32 -> fp16), cols = g*16+cc, k-major ----
    for (int u = tid; u < 64 * 76; u += 256) {
        int col = u / 76, k8 = u - col * 76;
        int g = col >> 4, cc = col & 15;
        int jh = nb * 16 + cc;
        int j = g * 300 + jh;
        f16x8 v;
        #pragma unroll
        for (int i = 0; i < 8; ++i) {
            int k = k8 * 8 + i;
            float x = 0.f;
            if (jh < 300) {
                if (k < 300)      x = Wih[(size_t)j * 300 + k];
                else if (k < 600) x = Whh[(size_t)j * 300 + (k - 300)];
            }
            v[i] = (f16)x;
        }
        *(f16x8*)&Wl[col * WLS + k8 * 8] = v;
    }

    // tokens for the 17 rows this wg stages within its mb block
    const int srow0 = nb * 17;
    for (int u = tid; u < 17 * TT; u += 256) {
        int rl = u / TT, t = u - rl * TT;
        int grow = mrow0 + srow0 + rl;
        capS[rl][t] = (srow0 + rl < 320 && grow < 4096) ? cap[(size_t)grow * TT + t] : 0;
    }
    if (tid < 2) {
        float s = 0.f;
        for (int k = 0; k < 300; ++k) { float v = v_wn[tid * 300 + k]; s += v * v; }
        scaleS[tid] = g_wn[tid] * rsqrtf(s);
    }
    __syncthreads();

    // ---- x staging: embed[tok] fp32 -> fp16 into exchange buffer ----
    auto stage_x = [&](int t, f16* bufn) {
        for (int u = tid; u < 17 * 38; u += 256) {
            int rl = u / 38, ch = u - rl * 38;
            int lrow = srow0 + rl;
            int grow = mrow0 + lrow;
            if (lrow >= 320 || grow >= 4096) continue;
            const float* er = embed + (size_t)capS[rl][t] * 300;
            f16* dst = bufn + (size_t)grow * XSTR;
            int k0 = ch * 8;
            if (ch < 37) {
                float4 a = *(const float4*)(er + k0);
                float4 bb = *(const float4*)(er + k0 + 4);
                f16x8 v;
                v[0] = (f16)a.x; v[1] = (f16)a.y; v[2] = (f16)a.z; v[3] = (f16)a.w;
                v[4] = (f16)bb.x; v[5] = (f16)bb.y; v[6] = (f16)bb.z; v[7] = (f16)bb.w;
                *(f16x8*)(dst + k0) = v;
            } else {
                #pragma unroll
                for (int i = 0; i < 4; ++i) dst[296 + i] = (f16)er[296 + i];
            }
        }
    };
    stage_x(0, buf0);

    // per-lane constants
    int aidx[5];
    #pragma unroll
    for (int m = 0; m < 5; ++m) {
        int row = mrow0 + (wv * 5 + m) * 16 + c;
        aidx[m] = row * XSTR + kg * 8;
    }
    int bbase[4];
    #pragma unroll
    for (int g = 0; g < 4; ++g) bbase[g] = (g * 16 + c) * WLS + kg * 8;

    const int jh = nb * 16 + c;
    float bias[4];
    #pragma unroll
    for (int g = 0; g < 4; ++g) {
        float bv = 0.f;
        if (jh < 300) { int j = g * 300 + jh; bv = bih[j] + bhh[j]; }
        bias[g] = bv;
    }
    int lenr[5][4];
    #pragma unroll
    for (int m = 0; m < 5; ++m) {
        int rb = mrow0 + (wv * 5 + m) * 16 + kg * 4;
        #pragma unroll
        for (int rg = 0; rg < 4; ++rg) {
            int row = rb + rg;
            lenr[m][rg] = (row < 4096) ? cap_len[row] : 0;
        }
    }

    float cst[5][4] = {};
    float hreg[5][4] = {};

    gbar();   // x0 visible everywhere

    #pragma unroll 1
    for (int t = 0; t < STEPS; ++t) {
        f16* bufc = (t & 1) ? buf1 : buf0;
        f16* bufn = (t & 1) ? buf0 : buf1;

        f32x4 acc[5][4];
        #pragma unroll
        for (int m = 0; m < 5; ++m)
            #pragma unroll
            for (int g = 0; g < 4; ++g) {
                float bv = bias[g];
                f32x4 b4 = {bv, bv, bv, bv};
                acc[m][g] = b4;
            }

        auto LOADCH = [&](f16x8 (&dst)[5], int kt) {
            #pragma unroll
            for (int m = 0; m < 5; ++m)
                dst[m] = *(const f16x8*)(bufc + aidx[m] + kt * 32);
        };
        auto COMPCH = [&](f16x8 (&src)[5], int kt) {
            #pragma unroll
            for (int g = 0; g < 4; ++g) {
                f16x8 bv = *(const f16x8*)&Wl[bbase[g] + kt * 32];
                #pragma unroll
                for (int m = 0; m < 5; ++m)
                    acc[m][g] = __builtin_amdgcn_mfma_f32_16x16x32_f16(src[m], bv, acc[m][g], 0, 0, 0);
            }
        };

        // 3-deep software pipeline over the 19 k-chunks (static reg indexing)
        f16x8 pa[5], pb[5], pc[5];
        LOADCH(pa, 0);  LOADCH(pb, 1);  LOADCH(pc, 2);
        COMPCH(pa, 0);  LOADCH(pa, 3);
        COMPCH(pb, 1);  LOADCH(pb, 4);
        COMPCH(pc, 2);  LOADCH(pc, 5);
        COMPCH(pa, 3);  LOADCH(pa, 6);
        COMPCH(pb, 4);  LOADCH(pb, 7);
        COMPCH(pc, 5);  LOADCH(pc, 8);
        COMPCH(pa, 6);  LOADCH(pa, 9);
        COMPCH(pb, 7);  LOADCH(pb, 10);
        COMPCH(pc, 8);  LOADCH(pc, 11);
        COMPCH(pa, 9);  LOADCH(pa, 12);
        COMPCH(pb, 10); LOADCH(pb, 13);
        COMPCH(pc, 11); LOADCH(pc, 14);
        COMPCH(pa, 12); LOADCH(pa, 15);
        COMPCH(pb, 13); LOADCH(pb, 16);
        COMPCH(pc, 14); LOADCH(pc, 17);
        COMPCH(pa, 15); LOADCH(pa, 18);
        COMPCH(pb, 16);
        COMPCH(pc, 17);
        COMPCH(pa, 18);

        // gate update (i/f/g/o same lane, different acc regs) + h store
        #pragma unroll
        for (int m = 0; m < 5; ++m) {
            #pragma unroll
            for (int rg = 0; rg < 4; ++rg) {
                bool upd = (t < lenr[m][rg]);
                float iv = sigm(acc[m][0][rg]);
                float fv = sigm(acc[m][1][rg]);
                float gv = tanh_f(acc[m][2][rg]);
                float ov = sigm(acc[m][3][rg]);
                float cn = fv * cst[m][rg] + iv * gv;
                cn = upd ? cn : cst[m][rg];
                cst[m][rg] = cn;
                float hn = ov * tanh_f(cn);
                hreg[m][rg] = upd ? hn : hreg[m][rg];
            }
            if (jh < 300) {
                int rb = mrow0 + (wv * 5 + m) * 16 + kg * 4;
                #pragma unroll
                for (int rg = 0; rg < 4; ++rg)
                    bufn[(size_t)(rb + rg) * XSTR + 300 + jh] = (f16)hreg[m][rg];
            }
        }

        if (t + 1 < STEPS) stage_x(t + 1, bufn);
        gbar();
    }

    // ---- head: rows [L*17, L*17+17), 2 classes, 4 k-segments ----
    const f16* hb = buf0;   // final h lives in buf[22&1] = buf0
    for (int u = tid; u < 136; u += 256) {
        int rl = u >> 3, cls = (u >> 2) & 1, seg = u & 3;
        int grow = L * 17 + rl;
        if (grow >= 4096) continue;
        float sc = scaleS[cls];
        const float* vr = v_wn + cls * 300 + seg * 75;
        const f16* hr = hb + (size_t)grow * XSTR + 300 + seg * 75;
        float s = 0.f;
        #pragma unroll 5
        for (int k = 0; k < 75; ++k) s += vr[k] * (float)hr[k];
        float part = sc * s + (seg == 0 ? b_cls[cls] : 0.f);
        atomicAdd(out + (size_t)grow * 2 + cls, part);
    }
}

extern "C" void kernel_launch(void* const* d_in, const int* in_sizes, int n_in,
                              void* d_out, int out_size, void* d_ws, size_t ws_size,
                              hipStream_t stream) {
    const int*   cap     = (const int*)  d_in[0];
    const int*   cap_len = (const int*)  d_in[1];
    const float* embed   = (const float*)d_in[2];
    const float* W_ih    = (const float*)d_in[3];
    const float* W_hh    = (const float*)d_in[4];
    const float* b_ih    = (const float*)d_in[5];
    const float* b_hh    = (const float*)d_in[6];
    const float* v_wn    = (const float*)d_in[7];
    const float* g_wn    = (const float*)d_in[8];
    const float* b_cls   = (const float*)d_in[9];
    float* out = (float*)d_out;

    unsigned* cnt = (unsigned*)d_ws;
    f16* b0 = (f16*)((char*)d_ws + 256);
    f16* b1 = b0 + BUFELT;

    size_t need = 256 + 2 * BUFELT * sizeof(f16);
    hipMemsetAsync(d_ws, 0, need, stream);                  // bufs + barrier cnt
    hipMemsetAsync(d_out, 0, (size_t)out_size * 4, stream); // head uses atomicAdd

    lstm_ws<<<NWG, 256, 0, stream>>>(cap, cap_len, embed, W_ih, W_hh, b_ih, b_hh,
                                     v_wn, g_wn, b_cls, b0, b1, cnt, out);
}

// Round 5
// 622.149 us; speedup vs baseline: 1.2034x; 1.2034x over previous
//
#include <hip/hip_runtime.h>
#include <hip/hip_fp16.h>

// Weight-stationary LSTM classifier. B=4096(+64 pad), T=22, E=H=300.
// Grid 248 = 8 XCDs x 31 slots; logical L = (b&7)*31 + b/8 (XCD-chunked for
// A-panel L2 locality). L<247: mb=L/19 (320 rows), nb=L%19 (16 jh x 4 gates).
// W block (64x608 fp16 = 79KB) LDS-stationary across all 22 steps.
// Per step: gates = A @ W (A=[x|h] fp16 global double-buffer), 3-deep
// register-pipelined A-chunks; i/f/g/o same-lane combine; h fp16 to other
// buffer; HIERARCHICAL device barrier (8 per-XCD lines + 1 global line)
// instead of 248 RMWs on one line; embed staging split issue-early/write-late.
// d_ws: [0,8KB) barrier lines, then 2 x 4160x608 fp16 buffers (10.1 MB).

#define TT 22
#define STEPS 22
#define NB 19
#define MBC 13
#define NACT (NB * MBC)          // 247 active
#define NWG 248                  // 8 x 31 (1 dummy, barrier-only)
#define XSTR 608                 // halves per A row (300 x | 300 h | 8 pad)
#define WLS 616                  // LDS W col stride (halves)
#define BUFROWS 4160
#define BUFELT ((size_t)BUFROWS * XSTR)

typedef _Float16 f16;
typedef _Float16 f16x4 __attribute__((ext_vector_type(4)));
typedef _Float16 f16x8 __attribute__((ext_vector_type(8)));
typedef float    f32x4 __attribute__((ext_vector_type(4)));

__device__ __forceinline__ float sigm(float x) { return 1.0f / (1.0f + __expf(-x)); }
__device__ __forceinline__ float tanh_f(float x) {
    float ax = fabsf(x);
    float e = __expf(-2.0f * ax);
    return copysignf((1.0f - e) / (1.0f + e), x);
}

__global__ __launch_bounds__(256, 1)
void lstm_ws(const int* __restrict__ cap, const int* __restrict__ cap_len,
             const float* __restrict__ embed,
             const float* __restrict__ Wih, const float* __restrict__ Whh,
             const float* __restrict__ bih, const float* __restrict__ bhh,
             const float* __restrict__ v_wn, const float* __restrict__ g_wn,
             const float* __restrict__ b_cls,
             f16* __restrict__ buf0, f16* __restrict__ buf1,
             unsigned* __restrict__ bar, float* __restrict__ out)
{
    __shared__ f16 Wl[64 * WLS];     // 78.8 KB stationary weights
    __shared__ int capS[17][TT];
    __shared__ float scaleS[2];

    const int tid = threadIdx.x;
    const int b   = blockIdx.x;
    const int grp = b & 7;                     // 8 groups x exactly 31
    const int L   = grp * 31 + (b >> 3);       // XCD-chunked logical id

    unsigned* locCnt  = bar + grp * 64;        // 256B-separated lines
    unsigned* locRel  = bar + 512 + grp * 64;
    unsigned* glob    = bar + 1024;
    unsigned* globRel = bar + 1088;

    unsigned bk = 0;
    auto gbar = [&]() {
        ++bk;
        __syncthreads();
        if (tid == 0) {
            unsigned old = __hip_atomic_fetch_add(locCnt, 1u, __ATOMIC_ACQ_REL,
                                                  __HIP_MEMORY_SCOPE_AGENT);
            if (old == bk * 31u - 1u) {        // last in group
                unsigned go = __hip_atomic_fetch_add(glob, 1u, __ATOMIC_ACQ_REL,
                                                     __HIP_MEMORY_SCOPE_AGENT);
                if (go == bk * 8u - 1u) {      // last group: release all
                    __hip_atomic_store(globRel, bk, __ATOMIC_RELEASE,
                                       __HIP_MEMORY_SCOPE_AGENT);
                } else {
                    while (__hip_atomic_load(globRel, __ATOMIC_RELAXED,
                                             __HIP_MEMORY_SCOPE_AGENT) < bk)
                        __builtin_amdgcn_s_sleep(2);
                    (void)__hip_atomic_load(globRel, __ATOMIC_ACQUIRE,
                                            __HIP_MEMORY_SCOPE_AGENT);
                }
                __hip_atomic_store(locRel, bk, __ATOMIC_RELEASE,
                                   __HIP_MEMORY_SCOPE_AGENT);
            } else {
                while (__hip_atomic_load(locRel, __ATOMIC_RELAXED,
                                         __HIP_MEMORY_SCOPE_AGENT) < bk)
                    __builtin_amdgcn_s_sleep(2);
                (void)__hip_atomic_load(locRel, __ATOMIC_ACQUIRE,
                                        __HIP_MEMORY_SCOPE_AGENT);
            }
        }
        __syncthreads();
    };

    if (L >= NACT) {                  // dummy wg: barriers only (23 total)
        for (int i = 0; i < STEPS + 1; ++i) gbar();
        return;
    }

    const int mb = L / NB;
    const int nb = L - mb * NB;
    const int mrow0 = mb * 320;
    const int wv = tid >> 6, ln = tid & 63, c = ln & 15, kg = ln >> 4;

    // ---- W block -> LDS (fp32 -> fp16), cols = g*16+cc, k-major ----
    for (int u = tid; u < 64 * 76; u += 256) {
        int col = u / 76, k8 = u - col * 76;
        int g = col >> 4, cc = col & 15;
        int jh = nb * 16 + cc;
        int j = g * 300 + jh;
        f16x8 v;
        #pragma unroll
        for (int i = 0; i < 8; ++i) {
            int k = k8 * 8 + i;
            float x = 0.f;
            if (jh < 300) {
                if (k < 300)      x = Wih[(size_t)j * 300 + k];
                else if (k < 600) x = Whh[(size_t)j * 300 + (k - 300)];
            }
            v[i] = (f16)x;
        }
        *(f16x8*)&Wl[col * WLS + k8 * 8] = v;
    }

    // tokens for the 17 rows this wg stages within its mb block
    const int srow0 = nb * 17;
    for (int u = tid; u < 17 * TT; u += 256) {
        int rl = u / TT, t = u - rl * TT;
        int grow = mrow0 + srow0 + rl;
        capS[rl][t] = (srow0 + rl < 320 && grow < 4096) ? cap[(size_t)grow * TT + t] : 0;
    }
    if (tid < 2) {
        float s = 0.f;
        for (int k = 0; k < 300; ++k) { float v = v_wn[tid * 300 + k]; s += v * v; }
        scaleS[tid] = g_wn[tid] * rsqrtf(s);
    }
    __syncthreads();

    // ---- async x staging: load-early (regs), write-late (bufn) ----
    float4 xa[3], xb[3];
    auto stageL = [&](int t) {
        #pragma unroll
        for (int it = 0; it < 3; ++it) {
            int u = tid + it * 256;
            if (u >= 646) continue;
            int rl = u / 38, ch = u - rl * 38;
            int lrow = srow0 + rl, grow = mrow0 + lrow;
            if (lrow >= 320 || grow >= 4096) continue;
            const float* er = embed + (size_t)capS[rl][t] * 300;
            int k0 = ch * 8;
            if (ch < 37) {
                xa[it] = *(const float4*)(er + k0);
                xb[it] = *(const float4*)(er + k0 + 4);
            } else {
                xa[it] = *(const float4*)(er + 296);
            }
        }
    };
    auto stageS = [&](f16* bufn) {
        #pragma unroll
        for (int it = 0; it < 3; ++it) {
            int u = tid + it * 256;
            if (u >= 646) continue;
            int rl = u / 38, ch = u - rl * 38;
            int lrow = srow0 + rl, grow = mrow0 + lrow;
            if (lrow >= 320 || grow >= 4096) continue;
            int k0 = ch * 8;
            f16* dst = bufn + (size_t)grow * XSTR + k0;
            if (ch < 37) {
                f16x8 v;
                v[0] = (f16)xa[it].x; v[1] = (f16)xa[it].y;
                v[2] = (f16)xa[it].z; v[3] = (f16)xa[it].w;
                v[4] = (f16)xb[it].x; v[5] = (f16)xb[it].y;
                v[6] = (f16)xb[it].z; v[7] = (f16)xb[it].w;
                *(f16x8*)dst = v;
            } else {
                f16x4 v;
                v[0] = (f16)xa[it].x; v[1] = (f16)xa[it].y;
                v[2] = (f16)xa[it].z; v[3] = (f16)xa[it].w;
                *(f16x4*)dst = v;
            }
        }
    };
    stageL(0); stageS(buf0);

    // per-lane constants
    int aidx[5];
    #pragma unroll
    for (int m = 0; m < 5; ++m) {
        int row = mrow0 + (wv * 5 + m) * 16 + c;
        aidx[m] = row * XSTR + kg * 8;
    }
    int bbase[4];
    #pragma unroll
    for (int g = 0; g < 4; ++g) bbase[g] = (g * 16 + c) * WLS + kg * 8;

    const int jh = nb * 16 + c;
    float bias[4];
    #pragma unroll
    for (int g = 0; g < 4; ++g) {
        float bv = 0.f;
        if (jh < 300) { int j = g * 300 + jh; bv = bih[j] + bhh[j]; }
        bias[g] = bv;
    }
    int lenr[5][4];
    #pragma unroll
    for (int m = 0; m < 5; ++m) {
        int rb = mrow0 + (wv * 5 + m) * 16 + kg * 4;
        #pragma unroll
        for (int rg = 0; rg < 4; ++rg) {
            int row = rb + rg;
            lenr[m][rg] = (row < 4096) ? cap_len[row] : 0;
        }
    }

    float cst[5][4] = {};
    float hreg[5][4] = {};

    gbar();   // x0 visible everywhere

    #pragma unroll 1
    for (int t = 0; t < STEPS; ++t) {
        f16* bufc = (t & 1) ? buf1 : buf0;
        f16* bufn = (t & 1) ? buf0 : buf1;

        f32x4 acc[5][4];
        #pragma unroll
        for (int m = 0; m < 5; ++m)
            #pragma unroll
            for (int g = 0; g < 4; ++g) {
                float bv = bias[g];
                f32x4 b4 = {bv, bv, bv, bv};
                acc[m][g] = b4;
            }

        auto LOADCH = [&](f16x8 (&dst)[5], int kt) {
            #pragma unroll
            for (int m = 0; m < 5; ++m)
                dst[m] = *(const f16x8*)(bufc + aidx[m] + kt * 32);
        };
        auto COMPCH = [&](f16x8 (&src)[5], int kt) {
            #pragma unroll
            for (int g = 0; g < 4; ++g) {
                f16x8 bv = *(const f16x8*)&Wl[bbase[g] + kt * 32];
                #pragma unroll
                for (int m = 0; m < 5; ++m)
                    acc[m][g] = __builtin_amdgcn_mfma_f32_16x16x32_f16(src[m], bv, acc[m][g], 0, 0, 0);
            }
        };

        // 3-deep software pipeline over the 19 k-chunks (static reg indexing)
        f16x8 pa[5], pb[5], pc[5];
        LOADCH(pa, 0);  LOADCH(pb, 1);  LOADCH(pc, 2);
        if (t + 1 < STEPS) stageL(t + 1);   // issue embed loads under MFMA
        COMPCH(pa, 0);  LOADCH(pa, 3);
        COMPCH(pb, 1);  LOADCH(pb, 4);
        COMPCH(pc, 2);  LOADCH(pc, 5);
        COMPCH(pa, 3);  LOADCH(pa, 6);
        COMPCH(pb, 4);  LOADCH(pb, 7);
        COMPCH(pc, 5);  LOADCH(pc, 8);
        COMPCH(pa, 6);  LOADCH(pa, 9);
        COMPCH(pb, 7);  LOADCH(pb, 10);
        COMPCH(pc, 8);  LOADCH(pc, 11);
        COMPCH(pa, 9);  LOADCH(pa, 12);
        COMPCH(pb, 10); LOADCH(pb, 13);
        COMPCH(pc, 11); LOADCH(pc, 14);
        COMPCH(pa, 12); LOADCH(pa, 15);
        COMPCH(pb, 13); LOADCH(pb, 16);
        COMPCH(pc, 14); LOADCH(pc, 17);
        COMPCH(pa, 15); LOADCH(pa, 18);
        COMPCH(pb, 16);
        COMPCH(pc, 17);
        COMPCH(pa, 18);

        // gate update (i/f/g/o same lane, different acc regs) + h store
        #pragma unroll
        for (int m = 0; m < 5; ++m) {
            #pragma unroll
            for (int rg = 0; rg < 4; ++rg) {
                bool upd = (t < lenr[m][rg]);
                float iv = sigm(acc[m][0][rg]);
                float fv = sigm(acc[m][1][rg]);
                float gv = tanh_f(acc[m][2][rg]);
                float ov = sigm(acc[m][3][rg]);
                float cn = fv * cst[m][rg] + iv * gv;
                cn = upd ? cn : cst[m][rg];
                cst[m][rg] = cn;
                float hn = ov * tanh_f(cn);
                hreg[m][rg] = upd ? hn : hreg[m][rg];
            }
            if (jh < 300) {
                int rb = mrow0 + (wv * 5 + m) * 16 + kg * 4;
                #pragma unroll
                for (int rg = 0; rg < 4; ++rg)
                    bufn[(size_t)(rb + rg) * XSTR + 300 + jh] = (f16)hreg[m][rg];
            }
        }

        if (t + 1 < STEPS) stageS(bufn);    // write-late x for next step
        gbar();
    }

    // ---- head: rows [L*17, L*17+17), 2 classes, 4 k-segments ----
    const f16* hb = buf0;   // final h lives in buf[22&1] = buf0
    for (int u = tid; u < 136; u += 256) {
        int rl = u >> 3, cls = (u >> 2) & 1, seg = u & 3;
        int grow = L * 17 + rl;
        if (grow >= 4096) continue;
        float sc = scaleS[cls];
        const float* vr = v_wn + cls * 300 + seg * 75;
        const f16* hr = hb + (size_t)grow * XSTR + 300 + seg * 75;
        float s = 0.f;
        #pragma unroll 5
        for (int k = 0; k < 75; ++k) s += vr[k] * (float)hr[k];
        float part = sc * s + (seg == 0 ? b_cls[cls] : 0.f);
        atomicAdd(out + (size_t)grow * 2 + cls, part);
    }
}

extern "C" void kernel_launch(void* const* d_in, const int* in_sizes, int n_in,
                              void* d_out, int out_size, void* d_ws, size_t ws_size,
                              hipStream_t stream) {
    const int*   cap     = (const int*)  d_in[0];
    const int*   cap_len = (const int*)  d_in[1];
    const float* embed   = (const float*)d_in[2];
    const float* W_ih    = (const float*)d_in[3];
    const float* W_hh    = (const float*)d_in[4];
    const float* b_ih    = (const float*)d_in[5];
    const float* b_hh    = (const float*)d_in[6];
    const float* v_wn    = (const float*)d_in[7];
    const float* g_wn    = (const float*)d_in[8];
    const float* b_cls   = (const float*)d_in[9];
    float* out = (float*)d_out;

    unsigned* bar = (unsigned*)d_ws;
    f16* b0 = (f16*)((char*)d_ws + 8192);
    f16* b1 = b0 + BUFELT;

    size_t need = 8192 + 2 * BUFELT * sizeof(f16);
    hipMemsetAsync(d_ws, 0, need, stream);                  // bufs + barrier lines
    hipMemsetAsync(d_out, 0, (size_t)out_size * 4, stream); // head uses atomicAdd

    lstm_ws<<<NWG, 256, 0, stream>>>(cap, cap_len, embed, W_ih, W_hh, b_ih, b_hh,
                                     v_wn, g_wn, b_cls, b0, b1, bar, out);
}